// Round 8
// baseline (278.939 us; speedup 1.0000x reference)
//
#include <hip/hip_runtime.h>

// B=8, T=2048, C=1024, H=64.  Reference: softmax over QUERY axis (dim=1),
// no 1/sqrt(d) scale.  out[t,h] = sum_{s<=t} exp(q_t.k_s)/D_s * v[s,h],
// D_s = sum_{t>=s} exp(q_t.k_s).
// Split-bf16 (hi+lo, 3-term) MFMA for qkv GEMM and QK dots (~fp32 accuracy);
// plain bf16 for V and P in PV (~0.4% rel).
// Round-8: occupancy. qkv M-tile 16 -> grid 1024 (4 blk/CU, 16 waves/CU);
// stats/out VGPR-trimmed + __launch_bounds__(256,4) -> 4 waves/SIMD.

typedef __attribute__((ext_vector_type(8))) short bf16x8;
typedef __attribute__((ext_vector_type(4))) float f32x4;
typedef unsigned short u16;

#define MFMA(a, b, c) __builtin_amdgcn_mfma_f32_16x16x32_bf16((a), (b), (c), 0, 0, 0)

__device__ __forceinline__ u16 f2bf(float x) {           // RNE fp32 -> bf16
    unsigned u = __float_as_uint(x);
    u += 0x7fff + ((u >> 16) & 1);
    return (u16)(u >> 16);
}
__device__ __forceinline__ float bf2f(u16 h) {
    return __uint_as_float(((unsigned)h) << 16);
}

// ws byte offsets
#define WH_OFF 0u
#define WL_OFF (WH_OFF + 192u*1024u*2u)
#define QH_OFF (WL_OFF + 192u*1024u*2u)
#define QL_OFF (QH_OFF + 8u*2048u*64u*2u)
#define KH_OFF (QL_OFF + 8u*2048u*64u*2u)
#define KL_OFF (KH_OFF + 8u*2048u*64u*2u)
#define VT_OFF (KL_OFF + 8u*2048u*64u*2u)
#define DD_OFF (VT_OFF + 8u*2048u*64u*2u)   // fp32 [B][T]

// ---------------------------------------------------------------------------
// W pre-split: rows 0..63 = Wq, 64..127 = Wk, 128..191 = Wv
// ---------------------------------------------------------------------------
__global__ __launch_bounds__(256) void wsplit_kernel(
    const float* __restrict__ Wk, const float* __restrict__ Wq,
    const float* __restrict__ Wv, u16* __restrict__ WH, u16* __restrict__ WL)
{
    const int n = blockIdx.x;
    const float* src = (n < 64) ? (Wq + (long)n * 1024)
                     : (n < 128) ? (Wk + (long)(n - 64) * 1024)
                                 : (Wv + (long)(n - 128) * 1024);
    const float4 f = ((const float4*)src)[threadIdx.x];
    const float v[4] = {f.x, f.y, f.z, f.w};
    u16 hi[4], lo[4];
    #pragma unroll
    for (int j = 0; j < 4; ++j) {
        hi[j] = f2bf(v[j]);
        lo[j] = f2bf(v[j] - bf2f(hi[j]));
    }
    *(ushort4*)&WH[(long)n * 1024 + 4 * threadIdx.x] = make_ushort4(hi[0], hi[1], hi[2], hi[3]);
    *(ushort4*)&WL[(long)n * 1024 + 4 * threadIdx.x] = make_ushort4(lo[0], lo[1], lo[2], lo[3]);
}

// ---------------------------------------------------------------------------
// qkv: [16384x1024] @ [1024x192].  M-tile 16 -> grid 1024 (4 blocks/CU,
// 16 waves/CU).  4 waves, wave w covers all 16 rows x 48 W-cols (nb=w*48).
// A-tile double-buffered LDS (split fp32 -> hi/lo); W frags direct global
// (L2-broadcast).  a_l rows: [hi 64 | lo 64 | pad 8] u16 = 272B.
// ---------------------------------------------------------------------------
__global__ __launch_bounds__(256, 4) void qkv_kernel(
    const float* __restrict__ idx, const u16* __restrict__ WH, const u16* __restrict__ WL,
    u16* __restrict__ QH, u16* __restrict__ QL,
    u16* __restrict__ KH, u16* __restrict__ KL, u16* __restrict__ VT)
{
    __shared__ u16 a_l[2][16 * 136];
    const int tid = threadIdx.x;
    const int w = tid >> 6, lr = tid & 15, quad = (tid >> 4) & 3;
    const int r0 = blockIdx.x * 16;
    const int b = r0 >> 11, t0 = r0 & 2047;
    const int nb = w * 48;
    const int sr = tid >> 4, sc = (tid & 15) * 4;   // staging: row, col-start
    const float* arow = &idx[(long)(r0 + sr) * 1024 + sc];

    f32x4 acc[3] = {};
    float4 pf;

    // prologue: stage chunk 0
    pf = *(const float4*)(arow);
    {
        const float vs[4] = {pf.x, pf.y, pf.z, pf.w};
        u16 hi[4], lo[4];
        #pragma unroll
        for (int j = 0; j < 4; ++j) {
            hi[j] = f2bf(vs[j]);
            lo[j] = f2bf(vs[j] - bf2f(hi[j]));
        }
        *(ushort4*)&a_l[0][sr * 136 + sc]      = make_ushort4(hi[0], hi[1], hi[2], hi[3]);
        *(ushort4*)&a_l[0][sr * 136 + 64 + sc] = make_ushort4(lo[0], lo[1], lo[2], lo[3]);
    }
    __syncthreads();

    int p = 0;
    for (int it = 0; it < 16; ++it) {
        const int c0 = it * 64;
        if (it < 15)    // register prefetch of next A chunk
            pf = *(const float4*)(arow + c0 + 64);

        // A frags from LDS (shared by all 4 waves)
        const int ar = lr * 136 + quad * 8;
        const bf16x8 ah0 = *(const bf16x8*)&a_l[p][ar];
        const bf16x8 ah1 = *(const bf16x8*)&a_l[p][ar + 32];
        const bf16x8 al0 = *(const bf16x8*)&a_l[p][ar + 64];
        const bf16x8 al1 = *(const bf16x8*)&a_l[p][ar + 96];

        #pragma unroll
        for (int nf = 0; nf < 3; ++nf) {
            const long wr = (long)(nb + nf * 16 + lr) * 1024 + c0 + quad * 8;
            const bf16x8 bh0 = *(const bf16x8*)&WH[wr];
            const bf16x8 bh1 = *(const bf16x8*)&WH[wr + 32];
            const bf16x8 bl0 = *(const bf16x8*)&WL[wr];
            const bf16x8 bl1 = *(const bf16x8*)&WL[wr + 32];
            f32x4 c = acc[nf];
            c = MFMA(ah0, bh0, c);
            c = MFMA(al0, bh0, c);
            c = MFMA(ah0, bl0, c);
            c = MFMA(ah1, bh1, c);
            c = MFMA(al1, bh1, c);
            c = MFMA(ah1, bl1, c);
            acc[nf] = c;
        }

        if (it < 15) {
            const float vs[4] = {pf.x, pf.y, pf.z, pf.w};
            u16 hi[4], lo[4];
            #pragma unroll
            for (int j = 0; j < 4; ++j) {
                hi[j] = f2bf(vs[j]);
                lo[j] = f2bf(vs[j] - bf2f(hi[j]));
            }
            *(ushort4*)&a_l[p ^ 1][sr * 136 + sc]      = make_ushort4(hi[0], hi[1], hi[2], hi[3]);
            *(ushort4*)&a_l[p ^ 1][sr * 136 + 64 + sc] = make_ushort4(lo[0], lo[1], lo[2], lo[3]);
            __syncthreads();
            p ^= 1;
        }
    }

    // epilogue: C layout col = lane&15 (n), row = quad*4 + reg (m)
    const int tb = t0 + quad * 4;
    #pragma unroll
    for (int nf = 0; nf < 3; ++nf) {
        const int n = nb + nf * 16 + lr;
        const f32x4 a = acc[nf];
        if (n < 128) {
            u16* Hd = (n < 64) ? QH : KH;
            u16* Ld = (n < 64) ? QL : KL;
            const int h = n & 63;
            #pragma unroll
            for (int r = 0; r < 4; ++r) {
                const float v = a[r];
                const u16 hi = f2bf(v);
                const u16 lo = f2bf(v - bf2f(hi));
                const long o = (long)(b * 2048 + tb + r) * 64 + h;
                Hd[o] = hi; Ld[o] = lo;
            }
        } else {
            *(ushort4*)&VT[(long)(b * 64 + n - 128) * 2048 + tb] =
                make_ushort4(f2bf(a[0]), f2bf(a[1]), f2bf(a[2]), f2bf(a[3]));
        }
    }
}

// ---------------------------------------------------------------------------
// stats: D_s = sum_{t>=s} exp(q_t.k_s).  K B-frags hoisted (64 VGPR);
// Q A-frags direct global per jt.  No LDS tiles, no in-loop barriers.
// Grid (144, B): s-tile i, t-chunk c (<=4 t-tiles); atomicAdd partials.
// ---------------------------------------------------------------------------
__global__ __launch_bounds__(256, 4) void stats_kernel(
    const u16* __restrict__ QH, const u16* __restrict__ QL,
    const u16* __restrict__ KH, const u16* __restrict__ KL,
    float* __restrict__ D)
{
    __shared__ float red[4][64];
    const int tid = threadIdx.x;
    const int w = tid >> 6, lr = tid & 15, quad = (tid >> 4) & 3;
    const int b = blockIdx.y;
    int x = blockIdx.x, i = 0;
    for (;;) { const int nc = (35 - i) >> 2; if (x < nc) break; x -= nc; ++i; }
    const int s0 = i * 64;
    const int jt0 = i + 4 * x, jt1 = min(jt0 + 4, 32);

    // hoist K B-frags for the whole loop (16 x bf16x8 = 64 VGPR)
    bf16x8 BH[4][2], BL[4][2];
    #pragma unroll
    for (int nf = 0; nf < 4; ++nf) {
        const long kr = (long)(b * 2048 + s0 + nf * 16 + lr) * 64 + quad * 8;
        BH[nf][0] = *(const bf16x8*)&KH[kr];
        BH[nf][1] = *(const bf16x8*)&KH[kr + 32];
        BL[nf][0] = *(const bf16x8*)&KL[kr];
        BL[nf][1] = *(const bf16x8*)&KL[kr + 32];
    }

    float dsum[4] = {0.f, 0.f, 0.f, 0.f};
    for (int jt = jt0; jt < jt1; ++jt) {
        const long qr = (long)(b * 2048 + jt * 64 + w * 16 + lr) * 64 + quad * 8;
        const bf16x8 ah0 = *(const bf16x8*)&QH[qr];
        const bf16x8 ah1 = *(const bf16x8*)&QH[qr + 32];
        const bf16x8 al0 = *(const bf16x8*)&QL[qr];
        const bf16x8 al1 = *(const bf16x8*)&QL[qr + 32];
        #pragma unroll
        for (int nf = 0; nf < 4; ++nf) {
            f32x4 cc = {};
            cc = MFMA(ah0, BH[nf][0], cc);
            cc = MFMA(al0, BH[nf][0], cc);
            cc = MFMA(ah0, BL[nf][0], cc);
            cc = MFMA(ah1, BH[nf][1], cc);
            cc = MFMA(al1, BH[nf][1], cc);
            cc = MFMA(ah1, BL[nf][1], cc);

            if (jt > i) {
                dsum[nf] += __expf(cc[0]) + __expf(cc[1]) + __expf(cc[2]) + __expf(cc[3]);
            } else {   // diagonal tile: include t >= s only
                const int sl = nf * 16 + lr;
                #pragma unroll
                for (int r = 0; r < 4; ++r) {
                    const int tl = w * 16 + quad * 4 + r;
                    if (tl >= sl) dsum[nf] += __expf(cc[r]);
                }
            }
        }
    }

    #pragma unroll
    for (int nf = 0; nf < 4; ++nf) {
        dsum[nf] += __shfl_xor(dsum[nf], 16);
        dsum[nf] += __shfl_xor(dsum[nf], 32);
    }
    if (quad == 0) {
        #pragma unroll
        for (int nf = 0; nf < 4; ++nf) red[w][nf * 16 + lr] = dsum[nf];
    }
    __syncthreads();
    if (tid < 64)
        atomicAdd(&D[b * 2048 + s0 + tid],
                  red[0][tid] + red[1][tid] + red[2][tid] + red[3][tid]);
}

// ---------------------------------------------------------------------------
// out: out[t][h] = sum_{s<=t} exp(q_t.k_s)/D_s * v[s][h].  Q A-frags hoisted
// (16 VGPR... 4 frags); K frags loaded per-nf (transient); VT burst (8 frags);
// wave-private LDS transpose; PV.  Grid (144, B): t-tile i, s-chunk c.
// ---------------------------------------------------------------------------
__global__ __launch_bounds__(256, 4) void out_kernel(
    const u16* __restrict__ QH, const u16* __restrict__ QL,
    const u16* __restrict__ KH, const u16* __restrict__ KL,
    const u16* __restrict__ VT, const float* __restrict__ D,
    float* __restrict__ out)
{
    __shared__ u16 wa[64 * 72];   // P [t][s], rows padded to 72
    const int tid = threadIdx.x;
    const int w = tid >> 6, lr = tid & 15, quad = (tid >> 4) & 3;
    const int b = blockIdx.y;
    int x = blockIdx.x, i = 0;
    for (;;) { const int nc = (i + 4) >> 2; if (x < nc) break; x -= nc; ++i; }
    const int t0 = i * 64;
    const int js0 = 4 * x, js1 = min(4 * x + 4, i + 1);

    // hoist q A-frags
    const long qr = (long)(b * 2048 + t0 + w * 16 + lr) * 64 + quad * 8;
    const bf16x8 qh0 = *(const bf16x8*)&QH[qr];
    const bf16x8 qh1 = *(const bf16x8*)&QH[qr + 32];
    const bf16x8 ql0 = *(const bf16x8*)&QL[qr];
    const bf16x8 ql1 = *(const bf16x8*)&QL[qr + 32];

    f32x4 oacc[4] = {};
    for (int js = js0; js < js1; ++js) {
        const int s0 = js * 64;
        const bool diag = (js == i);

        // dots (K frags transient per nf)
        f32x4 cc[4];
        float rv[4];
        #pragma unroll
        for (int nf = 0; nf < 4; ++nf) {
            const long kr = (long)(b * 2048 + s0 + nf * 16 + lr) * 64 + quad * 8;
            const bf16x8 bh0 = *(const bf16x8*)&KH[kr];
            const bf16x8 bh1 = *(const bf16x8*)&KH[kr + 32];
            const bf16x8 bl0 = *(const bf16x8*)&KL[kr];
            const bf16x8 bl1 = *(const bf16x8*)&KL[kr + 32];
            rv[nf] = D[b * 2048 + s0 + nf * 16 + lr];
            f32x4 c = {};
            c = MFMA(qh0, bh0, c);
            c = MFMA(ql0, bh0, c);
            c = MFMA(qh0, bl0, c);
            c = MFMA(qh1, bh1, c);
            c = MFMA(ql1, bh1, c);
            c = MFMA(qh1, bl1, c);
            cc[nf] = c;
        }

        // VT burst (lands during expf/transpose)
        bf16x8 VB[4][2];
        #pragma unroll
        for (int nf = 0; nf < 4; ++nf) {
            const long vr = (long)(b * 64 + nf * 16 + lr) * 2048 + s0 + quad * 8;
            VB[nf][0] = *(const bf16x8*)&VT[vr];
            VB[nf][1] = *(const bf16x8*)&VT[vr + 32];
        }

        // weights + wave-private transpose
        #pragma unroll
        for (int nf = 0; nf < 4; ++nf) {
            const int sl = nf * 16 + lr;
            const float r_ = 1.0f / rv[nf];
            #pragma unroll
            for (int r = 0; r < 4; ++r) {
                const int tl = w * 16 + quad * 4 + r;   // own wave's strip
                float pv = __expf(cc[nf][r]) * r_;
                if (diag && tl < sl) pv = 0.f;
                wa[tl * 72 + sl] = f2bf(pv);
            }
        }

        // PV
        #pragma unroll
        for (int kk = 0; kk < 2; ++kk) {
            const bf16x8 av = *(const bf16x8*)&wa[(w * 16 + lr) * 72 + kk * 32 + quad * 8];
            #pragma unroll
            for (int nf = 0; nf < 4; ++nf)
                oacc[nf] = MFMA(av, VB[nf][kk], oacc[nf]);
        }
    }

    const bool single = (i < 4);   // one chunk covers the whole row
    #pragma unroll
    for (int nf = 0; nf < 4; ++nf) {
        const int h = nf * 16 + lr;
        #pragma unroll
        for (int r = 0; r < 4; ++r) {
            const int t = t0 + w * 16 + quad * 4 + r;
            const long o = (long)(b * 2048 + t) * 64 + h;
            if (single) out[o] = oacc[nf][r];
            else        atomicAdd(&out[o], oacc[nf][r]);
        }
    }
}

extern "C" void kernel_launch(void* const* d_in, const int* in_sizes, int n_in,
                              void* d_out, int out_size, void* d_ws, size_t ws_size,
                              hipStream_t stream)
{
    const float* idx = (const float*)d_in[0];
    const float* Wk  = (const float*)d_in[1];
    const float* Wq  = (const float*)d_in[2];
    const float* Wv  = (const float*)d_in[3];
    char* ws = (char*)d_ws;
    float* out = (float*)d_out;

    u16* WH = (u16*)(ws + WH_OFF); u16* WL = (u16*)(ws + WL_OFF);
    u16* QH = (u16*)(ws + QH_OFF); u16* QL = (u16*)(ws + QL_OFF);
    u16* KH = (u16*)(ws + KH_OFF); u16* KL = (u16*)(ws + KL_OFF);
    u16* VT = (u16*)(ws + VT_OFF);
    float* Dp = (float*)(ws + DD_OFF);

    hipMemsetAsync(out, 0, (size_t)8 * 2048 * 64 * sizeof(float), stream);
    hipMemsetAsync(Dp, 0, (size_t)8 * 2048 * sizeof(float), stream);

    wsplit_kernel<<<192, 256, 0, stream>>>(Wk, Wq, Wv, WH, WL);
    qkv_kernel<<<1024, 256, 0, stream>>>(idx, WH, WL, QH, QL, KH, KL, VT);
    stats_kernel<<<dim3(144, 8), 256, 0, stream>>>(QH, QL, KH, KL, Dp);
    out_kernel<<<dim3(144, 8), 256, 0, stream>>>(QH, QL, KH, KL, VT, Dp, out);
}

// Round 9
// 185.634 us; speedup vs baseline: 1.5026x; 1.5026x over previous
//
#include <hip/hip_runtime.h>

// B=8, T=2048, C=1024, H=64.  Reference: softmax over QUERY axis (dim=1),
// no 1/sqrt(d) scale.  out[t,h] = sum_{s<=t} exp(q_t.k_s)/D_s * v[s,h],
// D_s = sum_{t>=s} exp(q_t.k_s).
// Split-bf16 (hi+lo, 3-term) MFMA for qkv GEMM and QK dots (~fp32 accuracy);
// plain bf16 for V and P in PV (~0.4% rel).
// Round-9: qkv M-tile 64 (halves W L2 traffic, the measured bottleneck:
// r6 402MB->63us vs r8 805MB->104us); stats/out reverted to the round-4
// LDS-staged versions (measured-best aggregate).

typedef __attribute__((ext_vector_type(8))) short bf16x8;
typedef __attribute__((ext_vector_type(4))) float f32x4;
typedef unsigned short u16;

#define MFMA(a, b, c) __builtin_amdgcn_mfma_f32_16x16x32_bf16((a), (b), (c), 0, 0, 0)

__device__ __forceinline__ u16 f2bf(float x) {           // RNE fp32 -> bf16
    unsigned u = __float_as_uint(x);
    u += 0x7fff + ((u >> 16) & 1);
    return (u16)(u >> 16);
}
__device__ __forceinline__ float bf2f(u16 h) {
    return __uint_as_float(((unsigned)h) << 16);
}

// ws byte offsets
#define WH_OFF 0u
#define WL_OFF (WH_OFF + 192u*1024u*2u)
#define QH_OFF (WL_OFF + 192u*1024u*2u)
#define QL_OFF (QH_OFF + 8u*2048u*64u*2u)
#define KH_OFF (QL_OFF + 8u*2048u*64u*2u)
#define KL_OFF (KH_OFF + 8u*2048u*64u*2u)
#define VT_OFF (KL_OFF + 8u*2048u*64u*2u)
#define DD_OFF (VT_OFF + 8u*2048u*64u*2u)   // fp32 [B][T]

// ---------------------------------------------------------------------------
// W pre-split: rows 0..63 = Wq, 64..127 = Wk, 128..191 = Wv
// ---------------------------------------------------------------------------
__global__ __launch_bounds__(256) void wsplit_kernel(
    const float* __restrict__ Wk, const float* __restrict__ Wq,
    const float* __restrict__ Wv, u16* __restrict__ WH, u16* __restrict__ WL)
{
    const int n = blockIdx.x;
    const float* src = (n < 64) ? (Wq + (long)n * 1024)
                     : (n < 128) ? (Wk + (long)(n - 64) * 1024)
                                 : (Wv + (long)(n - 128) * 1024);
    const float4 f = ((const float4*)src)[threadIdx.x];
    const float v[4] = {f.x, f.y, f.z, f.w};
    u16 hi[4], lo[4];
    #pragma unroll
    for (int j = 0; j < 4; ++j) {
        hi[j] = f2bf(v[j]);
        lo[j] = f2bf(v[j] - bf2f(hi[j]));
    }
    *(ushort4*)&WH[(long)n * 1024 + 4 * threadIdx.x] = make_ushort4(hi[0], hi[1], hi[2], hi[3]);
    *(ushort4*)&WL[(long)n * 1024 + 4 * threadIdx.x] = make_ushort4(lo[0], lo[1], lo[2], lo[3]);
}

// ---------------------------------------------------------------------------
// qkv: [16384x1024] @ [1024x192].  M-tile 64, 512 thr = 8 waves (2m x 4n:
// wave w -> m0=(w&1)*32, nb=(w>>1)*48).  A-tile double-buffered LDS
// (fp32 -> hi/lo split); W frags direct global (inline per nf, r6-best flow).
// a_l rows: [hi 64 | lo 64 | pad 8] u16 = 272B.  Grid 256, ~2 blocks/CU.
// ---------------------------------------------------------------------------
__global__ __launch_bounds__(512, 2) void qkv_kernel(
    const float* __restrict__ idx, const u16* __restrict__ WH, const u16* __restrict__ WL,
    u16* __restrict__ QH, u16* __restrict__ QL,
    u16* __restrict__ KH, u16* __restrict__ KL, u16* __restrict__ VT)
{
    __shared__ u16 a_l[2][64 * 136];
    const int tid = threadIdx.x;
    const int w = tid >> 6, lr = tid & 15, quad = (tid >> 4) & 3;
    const int r0 = blockIdx.x * 64;
    const int b = r0 >> 11, t0 = r0 & 2047;
    const int m0 = (w & 1) * 32;
    const int nb = (w >> 1) * 48;
    const int sr = tid >> 3, sc = (tid & 7) * 8;   // staging: row, col-start
    const float* arow = &idx[(long)(r0 + sr) * 1024 + sc];

    f32x4 acc[2][3] = {};
    float4 pf0, pf1;

    // prologue: stage chunk 0
    pf0 = *(const float4*)(arow);
    pf1 = *(const float4*)(arow + 4);
    {
        const float vs[8] = {pf0.x, pf0.y, pf0.z, pf0.w, pf1.x, pf1.y, pf1.z, pf1.w};
        bf16x8 hv, lv;
        #pragma unroll
        for (int j = 0; j < 8; ++j) {
            const u16 h = f2bf(vs[j]);
            hv[j] = (short)h;
            lv[j] = (short)f2bf(vs[j] - bf2f(h));
        }
        *(bf16x8*)&a_l[0][sr * 136 + sc]      = hv;
        *(bf16x8*)&a_l[0][sr * 136 + 64 + sc] = lv;
    }
    __syncthreads();

    int p = 0;
    for (int it = 0; it < 16; ++it) {
        const int c0 = it * 64;
        if (it < 15) {   // register prefetch of next A chunk
            pf0 = *(const float4*)(arow + c0 + 64);
            pf1 = *(const float4*)(arow + c0 + 68);
        }

        // A frags from LDS
        bf16x8 AH[2][2], AL[2][2];
        #pragma unroll
        for (int mi = 0; mi < 2; ++mi) {
            const int ar = (m0 + mi * 16 + lr) * 136 + quad * 8;
            AH[mi][0] = *(const bf16x8*)&a_l[p][ar];
            AH[mi][1] = *(const bf16x8*)&a_l[p][ar + 32];
            AL[mi][0] = *(const bf16x8*)&a_l[p][ar + 64];
            AL[mi][1] = *(const bf16x8*)&a_l[p][ar + 96];
        }

        #pragma unroll
        for (int nf = 0; nf < 3; ++nf) {
            const long wr = (long)(nb + nf * 16 + lr) * 1024 + c0 + quad * 8;
            const bf16x8 bh0 = *(const bf16x8*)&WH[wr];
            const bf16x8 bh1 = *(const bf16x8*)&WH[wr + 32];
            const bf16x8 bl0 = *(const bf16x8*)&WL[wr];
            const bf16x8 bl1 = *(const bf16x8*)&WL[wr + 32];
            #pragma unroll
            for (int mi = 0; mi < 2; ++mi) {
                f32x4 c = acc[mi][nf];
                c = MFMA(AH[mi][0], bh0, c);
                c = MFMA(AL[mi][0], bh0, c);
                c = MFMA(AH[mi][0], bl0, c);
                c = MFMA(AH[mi][1], bh1, c);
                c = MFMA(AL[mi][1], bh1, c);
                c = MFMA(AH[mi][1], bl1, c);
                acc[mi][nf] = c;
            }
        }

        if (it < 15) {
            const float vs[8] = {pf0.x, pf0.y, pf0.z, pf0.w, pf1.x, pf1.y, pf1.z, pf1.w};
            bf16x8 hv, lv;
            #pragma unroll
            for (int j = 0; j < 8; ++j) {
                const u16 h = f2bf(vs[j]);
                hv[j] = (short)h;
                lv[j] = (short)f2bf(vs[j] - bf2f(h));
            }
            *(bf16x8*)&a_l[p ^ 1][sr * 136 + sc]      = hv;
            *(bf16x8*)&a_l[p ^ 1][sr * 136 + 64 + sc] = lv;
            __syncthreads();
            p ^= 1;
        }
    }

    // epilogue: C layout col = lane&15 (n), row = quad*4 + reg (m)
    #pragma unroll
    for (int mi = 0; mi < 2; ++mi) {
        const int tb = t0 + m0 + mi * 16 + quad * 4;
        #pragma unroll
        for (int nf = 0; nf < 3; ++nf) {
            const int n = nb + nf * 16 + lr;
            const f32x4 a = acc[mi][nf];
            if (n < 128) {
                u16* Hd = (n < 64) ? QH : KH;
                u16* Ld = (n < 64) ? QL : KL;
                const int h = n & 63;
                #pragma unroll
                for (int r = 0; r < 4; ++r) {
                    const float v = a[r];
                    const u16 hi = f2bf(v);
                    const u16 lo = f2bf(v - bf2f(hi));
                    const long o = (long)(b * 2048 + tb + r) * 64 + h;
                    Hd[o] = hi; Ld[o] = lo;
                }
            } else {
                *(ushort4*)&VT[(long)(b * 64 + n - 128) * 2048 + tb] =
                    make_ushort4(f2bf(a[0]), f2bf(a[1]), f2bf(a[2]), f2bf(a[3]));
            }
        }
    }
}

// ---------------------------------------------------------------------------
// stats (round-4 verbatim): D_s = sum_{t>=s} exp(q_t.k_s).  LDS-staged kt/qt,
// 6-mfma split dots.  Grid (80, B): s-tile i, t-chunk c (<=8); atomicAdd.
// ---------------------------------------------------------------------------
__global__ __launch_bounds__(256) void stats_kernel(
    const u16* __restrict__ QH, const u16* __restrict__ QL,
    const u16* __restrict__ KH, const u16* __restrict__ KL,
    float* __restrict__ D)
{
    __shared__ u16 kt[64 * 136];
    __shared__ u16 qt[64 * 136];
    __shared__ float red[4][64];
    const int tid = threadIdx.x;
    const int w = tid >> 6, lr = tid & 15, quad = (tid >> 4) & 3;
    const int b = blockIdx.y;
    int x = blockIdx.x, i = 0;
    for (;;) { const int nc = (39 - i) >> 3; if (x < nc) break; x -= nc; ++i; }
    const int c = x;
    const int s0 = i * 64;

    #pragma unroll
    for (int it = 0; it < 2; ++it) {
        const int e = it * 256 + tid;
        const int s = e >> 3, c8 = e & 7;
        const long g = (long)(b * 2048 + s0 + s) * 64 + 8 * c8;
        *(float4*)&kt[s * 136 + 8 * c8]      = *(const float4*)&KH[g];
        *(float4*)&kt[s * 136 + 64 + 8 * c8] = *(const float4*)&KL[g];
    }

    float dsum[4] = {0.f, 0.f, 0.f, 0.f};
    const int ar = (w * 16 + lr) * 136;
    const int jt1 = min(i + 8 * c + 8, 32);
    for (int jt = i + 8 * c; jt < jt1; ++jt) {
        __syncthreads();
        #pragma unroll
        for (int it = 0; it < 2; ++it) {
            const int e = it * 256 + tid;
            const int t = e >> 3, c8 = e & 7;
            const long g = (long)(b * 2048 + jt * 64 + t) * 64 + 8 * c8;
            *(float4*)&qt[t * 136 + 8 * c8]      = *(const float4*)&QH[g];
            *(float4*)&qt[t * 136 + 64 + 8 * c8] = *(const float4*)&QL[g];
        }
        __syncthreads();

        const bf16x8 ah0 = *(const bf16x8*)&qt[ar + quad * 8];
        const bf16x8 al0 = *(const bf16x8*)&qt[ar + 64 + quad * 8];
        const bf16x8 ah1 = *(const bf16x8*)&qt[ar + 32 + quad * 8];
        const bf16x8 al1 = *(const bf16x8*)&qt[ar + 96 + quad * 8];
        #pragma unroll
        for (int nf = 0; nf < 4; ++nf) {
            const int br = (nf * 16 + lr) * 136;
            f32x4 cc = {};
            const bf16x8 bh0 = *(const bf16x8*)&kt[br + quad * 8];
            const bf16x8 bl0 = *(const bf16x8*)&kt[br + 64 + quad * 8];
            cc = MFMA(ah0, bh0, cc); cc = MFMA(ah0, bl0, cc); cc = MFMA(al0, bh0, cc);
            const bf16x8 bh1 = *(const bf16x8*)&kt[br + 32 + quad * 8];
            const bf16x8 bl1 = *(const bf16x8*)&kt[br + 96 + quad * 8];
            cc = MFMA(ah1, bh1, cc); cc = MFMA(ah1, bl1, cc); cc = MFMA(al1, bh1, cc);

            if (jt > i) {
                dsum[nf] += __expf(cc[0]) + __expf(cc[1]) + __expf(cc[2]) + __expf(cc[3]);
            } else {   // diagonal tile: include t >= s
                const int sl = nf * 16 + lr;
                #pragma unroll
                for (int r = 0; r < 4; ++r) {
                    const int tl = w * 16 + quad * 4 + r;
                    if (tl >= sl) dsum[nf] += __expf(cc[r]);
                }
            }
        }
    }

    #pragma unroll
    for (int nf = 0; nf < 4; ++nf) {
        dsum[nf] += __shfl_xor(dsum[nf], 16);
        dsum[nf] += __shfl_xor(dsum[nf], 32);
    }
    if (quad == 0) {
        #pragma unroll
        for (int nf = 0; nf < 4; ++nf) red[w][nf * 16 + lr] = dsum[nf];
    }
    __syncthreads();
    if (tid < 64)
        atomicAdd(&D[b * 2048 + s0 + tid],
                  red[0][tid] + red[1][tid] + red[2][tid] + red[3][tid]);
}

// ---------------------------------------------------------------------------
// out (round-4 verbatim): per t-tile, loop s-tiles <= t.  LDS-staged kt/vt,
// split dots -> w = exp * (1/D_s) masked -> bf16 LDS wa (A-layout, own-wave
// strip) -> PV mfma -> store / atomicAdd.  Grid (80, B).
// ---------------------------------------------------------------------------
__global__ __launch_bounds__(256) void out_kernel(
    const u16* __restrict__ QH, const u16* __restrict__ QL,
    const u16* __restrict__ KH, const u16* __restrict__ KL,
    const u16* __restrict__ VT, const float* __restrict__ D,
    float* __restrict__ out)
{
    __shared__ u16 qt[64 * 136];
    __shared__ u16 kt[64 * 136];
    __shared__ u16 vt[64 * 72];
    __shared__ u16 wa[64 * 72];
    __shared__ float rdt[64];
    const int tid = threadIdx.x;
    const int w = tid >> 6, lr = tid & 15, quad = (tid >> 4) & 3;
    const int b = blockIdx.y;
    int x = blockIdx.x, i = 0;
    for (;;) { const int nc = (i + 8) >> 3; if (x < nc) break; x -= nc; ++i; }
    const int c = x;
    const int t0 = i * 64;

    #pragma unroll
    for (int it = 0; it < 2; ++it) {   // stage Q tile once
        const int e = it * 256 + tid;
        const int t = e >> 3, c8 = e & 7;
        const long g = (long)(b * 2048 + t0 + t) * 64 + 8 * c8;
        *(float4*)&qt[t * 136 + 8 * c8]      = *(const float4*)&QH[g];
        *(float4*)&qt[t * 136 + 64 + 8 * c8] = *(const float4*)&QL[g];
    }

    f32x4 oacc[4] = {};
    const int ar = (w * 16 + lr) * 136;
    const int js1 = min(8 * c + 8, i + 1);
    for (int js = 8 * c; js < js1; ++js) {
        const int s0 = js * 64;
        __syncthreads();
        #pragma unroll
        for (int it = 0; it < 2; ++it) {
            const int e = it * 256 + tid;
            const int s = e >> 3, c8 = e & 7;
            const long g = (long)(b * 2048 + s0 + s) * 64 + 8 * c8;
            *(float4*)&kt[s * 136 + 8 * c8]      = *(const float4*)&KH[g];
            *(float4*)&kt[s * 136 + 64 + 8 * c8] = *(const float4*)&KL[g];
        }
        #pragma unroll
        for (int it = 0; it < 2; ++it) {
            const int e = it * 256 + tid;
            const int h = e >> 3, c8 = e & 7;
            *(float4*)&vt[h * 72 + 8 * c8] =
                *(const float4*)&VT[(long)(b * 64 + h) * 2048 + s0 + 8 * c8];
        }
        if (tid < 64) rdt[tid] = 1.0f / D[b * 2048 + s0 + tid];
        __syncthreads();

        // dot phase (wave strip: t rows w*16..w*16+15)
        const bf16x8 ah0 = *(const bf16x8*)&qt[ar + quad * 8];
        const bf16x8 al0 = *(const bf16x8*)&qt[ar + 64 + quad * 8];
        const bf16x8 ah1 = *(const bf16x8*)&qt[ar + 32 + quad * 8];
        const bf16x8 al1 = *(const bf16x8*)&qt[ar + 96 + quad * 8];
        const bool diag = (js == i);
        #pragma unroll
        for (int nf = 0; nf < 4; ++nf) {
            const int br = (nf * 16 + lr) * 136;
            f32x4 cc = {};
            const bf16x8 bh0 = *(const bf16x8*)&kt[br + quad * 8];
            const bf16x8 bl0 = *(const bf16x8*)&kt[br + 64 + quad * 8];
            cc = MFMA(ah0, bh0, cc); cc = MFMA(ah0, bl0, cc); cc = MFMA(al0, bh0, cc);
            const bf16x8 bh1 = *(const bf16x8*)&kt[br + 32 + quad * 8];
            const bf16x8 bl1 = *(const bf16x8*)&kt[br + 96 + quad * 8];
            cc = MFMA(ah1, bh1, cc); cc = MFMA(ah1, bl1, cc); cc = MFMA(al1, bh1, cc);

            const int sl = nf * 16 + lr;
            const float rv = rdt[sl];
            #pragma unroll
            for (int r = 0; r < 4; ++r) {
                const int tl = w * 16 + quad * 4 + r;
                float wgt = __expf(cc[r]) * rv;
                if (diag && tl < sl) wgt = 0.f;
                wa[tl * 72 + sl] = f2bf(wgt);     // own-wave strip only
            }
        }
        // PV: A = wa strip (own rows), B = vt [h][s]
        #pragma unroll
        for (int kk = 0; kk < 2; ++kk) {
            const bf16x8 av = *(const bf16x8*)&wa[(w * 16 + lr) * 72 + kk * 32 + quad * 8];
            #pragma unroll
            for (int nf = 0; nf < 4; ++nf) {
                const bf16x8 bv = *(const bf16x8*)&vt[(nf * 16 + lr) * 72 + kk * 32 + quad * 8];
                oacc[nf] = MFMA(av, bv, oacc[nf]);
            }
        }
    }

    const bool single = (i < 8);
    #pragma unroll
    for (int nf = 0; nf < 4; ++nf) {
        const int h = nf * 16 + lr;
        #pragma unroll
        for (int r = 0; r < 4; ++r) {
            const int t = t0 + w * 16 + quad * 4 + r;
            const long o = (long)(b * 2048 + t) * 64 + h;
            if (single) out[o] = oacc[nf][r];
            else        atomicAdd(&out[o], oacc[nf][r]);
        }
    }
}

extern "C" void kernel_launch(void* const* d_in, const int* in_sizes, int n_in,
                              void* d_out, int out_size, void* d_ws, size_t ws_size,
                              hipStream_t stream)
{
    const float* idx = (const float*)d_in[0];
    const float* Wk  = (const float*)d_in[1];
    const float* Wq  = (const float*)d_in[2];
    const float* Wv  = (const float*)d_in[3];
    char* ws = (char*)d_ws;
    float* out = (float*)d_out;

    u16* WH = (u16*)(ws + WH_OFF); u16* WL = (u16*)(ws + WL_OFF);
    u16* QH = (u16*)(ws + QH_OFF); u16* QL = (u16*)(ws + QL_OFF);
    u16* KH = (u16*)(ws + KH_OFF); u16* KL = (u16*)(ws + KL_OFF);
    u16* VT = (u16*)(ws + VT_OFF);
    float* Dp = (float*)(ws + DD_OFF);

    hipMemsetAsync(out, 0, (size_t)8 * 2048 * 64 * sizeof(float), stream);
    hipMemsetAsync(Dp, 0, (size_t)8 * 2048 * sizeof(float), stream);

    wsplit_kernel<<<192, 256, 0, stream>>>(Wk, Wq, Wv, WH, WL);
    qkv_kernel<<<256, 512, 0, stream>>>(idx, WH, WL, QH, QL, KH, KL, VT);
    stats_kernel<<<dim3(80, 8), 256, 0, stream>>>(QH, QL, KH, KL, Dp);
    out_kernel<<<dim3(80, 8), 256, 0, stream>>>(QH, QL, KH, KL, VT, Dp, out);
}